// Round 1
// baseline (368.893 us; speedup 1.0000x reference)
//
#include <hip/hip_runtime.h>
#include <cstdint>
#include <cstddef>

// Problem constants (from reference)
#define BB      512
#define CC      256
#define KXX     6
#define KZZ     22
#define HO      17                 // 22 - 6 + 1
#define OUTHW   (HO * HO)          // 289
#define ZCH     (KZZ * KZZ)        // 484 floats per (b,c) of z
#define XCH     (KXX * KXX)        // 36 floats per (b,c) of x

// Tiling
#define CHUNK_C   8                          // channels staged per chunk
#define ZCHUNK    (CHUNK_C * ZCH)            // 3872 floats = 15488 B
#define XCHUNK    (CHUNK_C * XCH)            // 288 floats  = 1152 B
#define NT        320                        // 5 waves
#define SPLITC    4                          // blocks per sample (C split)

typedef const __attribute__((address_space(1))) void* gptr_t;
typedef __attribute__((address_space(3))) void* lptr_t;

// Async global->LDS. LDS dest is WAVE-UNIFORM base; HW scatters lane i to
// base + i*size. Global addr is per-lane.
__device__ __forceinline__ void cp16_async(void* lds_base, const void* gsrc) {
  __builtin_amdgcn_global_load_lds((gptr_t)gsrc, (lptr_t)lds_base, 16, 0, 0);
}
__device__ __forceinline__ void cp4_async(void* lds_base, const void* gsrc) {
  __builtin_amdgcn_global_load_lds((gptr_t)gsrc, (lptr_t)lds_base, 4, 0, 0);
}

// Stage one chunk: z = 15488 B (15 x 1024 B + 128 B tail),
//                  x = 1152 B  (1 x 1024 B + 128 B tail).
__device__ __forceinline__ void stage_chunk(float* zdst, float* xdst,
                                            const float* zsrc, const float* xsrc,
                                            int wave, int lane) {
  char* zd = (char*)zdst;
  const char* zs = (const char*)zsrc;
#pragma unroll
  for (int i = 0; i < 3; ++i) {               // 15 full 1 KiB groups, 3 per wave
    const int grp = wave * 3 + i;
    cp16_async(zd + grp * 1024, zs + grp * 1024 + lane * 16);
  }
  if (wave == 0) {
    if (lane < 32) cp4_async(zd + 15360, zs + 15360 + lane * 4);   // z tail 128 B
  } else if (wave == 1) {
    cp16_async((char*)xdst, (const char*)xsrc + lane * 16);        // x 1024 B
  } else if (wave == 2) {
    if (lane < 32) cp4_async((char*)xdst + 1024, (const char*)xsrc + 1024 + lane * 4);
  }
}

// SPLIT: how many blocks share one sample b (each handles CC/SPLIT channels).
// SPLIT==1 writes directly to out; SPLIT>1 writes partials to ws.
template <int SPLIT>
__global__ __launch_bounds__(NT, 4) void corr_kernel(const float* __restrict__ x,
                                                     const float* __restrict__ z,
                                                     float* __restrict__ dst) {
  constexpr int CPB = CC / SPLIT;              // channels per block
  constexpr int NCH = CPB / CHUNK_C;           // chunks per block

  // 2*15488 + 2*1152 = 33280 B LDS -> 4 blocks/CU by LDS; VGPR cap gives 3.
  __shared__ __align__(16) float zbuf[2][ZCHUNK];
  __shared__ __align__(16) float xbuf[2][XCHUNK];

  const int bid  = blockIdx.x;
  const int b    = bid / SPLIT;                // SPLIT is 1 or 4 (pow2, cheap)
  const int s    = bid & (SPLIT - 1);
  const int t    = threadIdx.x;
  const int wave = t >> 6;
  const int lane = t & 63;

  const float* zb = z + (size_t)b * (CC * ZCH) + (size_t)s * (CPB * ZCH);
  const float* xb = x + (size_t)b * (CC * XCH) + (size_t)s * (CPB * XCH);

  // Prefetch chunk 0
  stage_chunk(zbuf[0], xbuf[0], zb, xb, wave, lane);

  // Compute mapping: 272 active threads = 16 groups x 17 output rows.
  // group g = (channel-within-chunk cl 0..7) x (ky half 0..1)
  const int  g      = t / 17;
  const int  oy     = t - g * 17;
  const int  cl     = g & 7;
  const int  kyh    = g >> 3;           // 0: ky 0..2, 1: ky 3..5
  const bool active = (g < 16);

  float acc[HO];
#pragma unroll
  for (int i = 0; i < HO; ++i) acc[i] = 0.0f;

  for (int k = 0; k < NCH; ++k) {
    const int buf = k & 1;
    __syncthreads();   // drains chunk-k loads (vmcnt) + all LDS reads of buf^1

    // Prefetch next chunk into the other buffer; stays in flight during compute.
    if (k + 1 < NCH)
      stage_chunk(zbuf[buf ^ 1], xbuf[buf ^ 1],
                  zb + (size_t)(k + 1) * ZCHUNK, xb + (size_t)(k + 1) * XCHUNK,
                  wave, lane);

    if (active) {
      const float* zc = &zbuf[buf][cl * ZCH];
      const float* xc = &xbuf[buf][cl * XCH + kyh * (3 * KXX)];

      __align__(16) float xv[3 * KXX];
#pragma unroll
      for (int i = 0; i < 9; ++i)
        ((float2*)xv)[i] = ((const float2*)xc)[i];   // ds_read_b64, broadcast-ish

#pragma unroll
      for (int ky2 = 0; ky2 < 3; ++ky2) {
        const int row = oy + kyh * 3 + ky2;
        const float* zr = zc + row * KZZ;
        __align__(16) float zv[KZZ + 1];
#pragma unroll
        for (int i = 0; i < 11; ++i)
          ((float2*)zv)[i] = ((const float2*)zr)[i]; // 11 ds_read_b64, row in regs
#pragma unroll
        for (int kx = 0; kx < KXX; ++kx) {
          const float xs = xv[ky2 * KXX + kx];
#pragma unroll
          for (int ox = 0; ox < HO; ++ox)
            acc[ox] = fmaf(zv[ox + kx], xs, acc[ox]); // 17-wide register reuse
        }
      }
    }
  }

  // Cross-group reduction: 16 partials per output. Reuse zbuf as scratch.
  __syncthreads();
  float* red = &zbuf[0][0];   // needs 16*289 = 4624 floats <= 7744 available
  if (active) {
#pragma unroll
    for (int ox = 0; ox < HO; ++ox)
      red[g * OUTHW + oy * HO + ox] = acc[ox];
  }
  __syncthreads();
  if (t < OUTHW) {
    float v = 0.0f;
#pragma unroll
    for (int gg = 0; gg < 16; ++gg) v += red[gg * OUTHW + t];
    dst[(size_t)bid * OUTHW + t] = v;   // coalesced: consecutive t -> consecutive addr
  }
}

// Sum the SPLITC partials per sample: out[b] = sum_s ws[b*SPLITC + s]
__global__ __launch_bounds__(NT) void reduce_kernel(const float* __restrict__ ws,
                                                    float* __restrict__ out) {
  const int b = blockIdx.x;
  const int t = threadIdx.x;
  if (t < OUTHW) {
    float v = 0.0f;
#pragma unroll
    for (int s = 0; s < SPLITC; ++s)
      v += ws[(size_t)(b * SPLITC + s) * OUTHW + t];
    out[(size_t)b * OUTHW + t] = v;
  }
}

extern "C" void kernel_launch(void* const* d_in, const int* in_sizes, int n_in,
                              void* d_out, int out_size, void* d_ws, size_t ws_size,
                              hipStream_t stream) {
  const float* x = (const float*)d_in[0];   // [512,256,6,6]
  const float* z = (const float*)d_in[1];   // [512,256,22,22]
  float* out = (float*)d_out;               // [512,1,17,17]

  const size_t need = (size_t)BB * SPLITC * OUTHW * sizeof(float);  // 2.37 MB
  if (ws_size >= need) {
    float* ws = (float*)d_ws;
    corr_kernel<SPLITC><<<BB * SPLITC, NT, 0, stream>>>(x, z, ws);
    reduce_kernel<<<BB, NT, 0, stream>>>(ws, out);
  } else {
    // Workspace too small: single-pass fallback (previous verified layout).
    corr_kernel<1><<<BB, NT, 0, stream>>>(x, z, out);
  }
}

// Round 2
// 360.380 us; speedup vs baseline: 1.0236x; 1.0236x over previous
//
#include <hip/hip_runtime.h>
#include <cstdint>
#include <cstddef>

// Problem constants (from reference)
#define BB      512
#define CC      256
#define KXX     6
#define KZZ     22
#define HO      17                 // 22 - 6 + 1
#define OUTHW   (HO * HO)          // 289
#define ZCH     (KZZ * KZZ)        // 484 floats per (b,c) of z
#define XCH     (KXX * KXX)        // 36 floats per (b,c) of x

// Tiling
#define CHUNK_C   8                          // channels staged per chunk
#define NCHUNK    (CC / CHUNK_C)             // 32
#define ZCHUNK    (CHUNK_C * ZCH)            // 3872 floats = 15488 B
#define XCHUNK    (CHUNK_C * XCH)            // 288 floats  = 1152 B
#define NT        320                        // 5 waves
#define NW        5

typedef const __attribute__((address_space(1))) void* gptr_t;
typedef __attribute__((address_space(3))) void* lptr_t;

// Async global->LDS. LDS dest is WAVE-UNIFORM base; HW scatters lane i to
// base + i*size. Global addr is per-lane.
__device__ __forceinline__ void cp16_async(void* lds_base, const void* gsrc) {
  __builtin_amdgcn_global_load_lds((gptr_t)gsrc, (lptr_t)lds_base, 16, 0, 0);
}
__device__ __forceinline__ void cp4_async(void* lds_base, const void* gsrc) {
  __builtin_amdgcn_global_load_lds((gptr_t)gsrc, (lptr_t)lds_base, 4, 0, 0);
}

// Stage one chunk: z = 15488 B (15 x 1024 B + 128 B tail),
//                  x = 1152 B  (1 x 1024 B + 128 B tail).
__device__ __forceinline__ void stage_chunk(float* zdst, float* xdst,
                                            const float* zsrc, const float* xsrc,
                                            int wave, int lane) {
  char* zd = (char*)zdst;
  const char* zs = (const char*)zsrc;
#pragma unroll
  for (int i = 0; i < 3; ++i) {               // 15 full 1 KiB groups, 3 per wave
    const int grp = wave * 3 + i;
    cp16_async(zd + grp * 1024, zs + grp * 1024 + lane * 16);
  }
  if (wave == 0) {
    if (lane < 32) cp4_async(zd + 15360, zs + 15360 + lane * 4);   // z tail 128 B
  } else if (wave == 1) {
    cp16_async((char*)xdst, (const char*)xsrc + lane * 16);        // x 1024 B
  } else if (wave == 2) {
    if (lane < 32) cp4_async((char*)xdst + 1024, (const char*)xsrc + 1024 + lane * 4);
  }
}

__global__ __launch_bounds__(NT, 2) void corr_kernel(const float* __restrict__ x,
                                                     const float* __restrict__ z,
                                                     float* __restrict__ out) {
  // 2*15488 + 2*1152 = 33280 B LDS -> 2 blocks/CU (512 blocks = 2 per CU exactly)
  __shared__ __align__(16) float zbuf[2][ZCHUNK];
  __shared__ __align__(16) float xbuf[2][XCHUNK];

  const int b    = blockIdx.x;
  const int t    = threadIdx.x;
  const int wave = t >> 6;
  const int lane = t & 63;

  const float* zb = z + (size_t)b * (CC * ZCH);
  const float* xb = x + (size_t)b * (CC * XCH);

  // Prefetch chunk 0
  stage_chunk(zbuf[0], xbuf[0], zb, xb, wave, lane);

  // Compute mapping: 272 active threads = 16 groups x 17 output rows.
  // group g = (channel-within-chunk cl 0..7) x (ky half 0..1)
  const int  g      = t / 17;
  const int  oy     = t - g * 17;
  const int  cl     = g & 7;
  const int  kyh    = g >> 3;           // 0: ky 0..2, 1: ky 3..5
  const bool active = (g < 16);

  float acc[HO];
#pragma unroll
  for (int i = 0; i < HO; ++i) acc[i] = 0.0f;

  for (int k = 0; k < NCHUNK; ++k) {
    const int buf = k & 1;
    __syncthreads();   // drains chunk-k loads (vmcnt) + all LDS reads of buf^1

    // Prefetch next chunk into the other buffer; stays in flight during compute.
    if (k + 1 < NCHUNK)
      stage_chunk(zbuf[buf ^ 1], xbuf[buf ^ 1],
                  zb + (size_t)(k + 1) * ZCHUNK, xb + (size_t)(k + 1) * XCHUNK,
                  wave, lane);

    if (active) {
      const float* zc = &zbuf[buf][cl * ZCH];
      const float* xc = &xbuf[buf][cl * XCH + kyh * (3 * KXX)];

      __align__(16) float xv[3 * KXX];
#pragma unroll
      for (int i = 0; i < 9; ++i)
        ((float2*)xv)[i] = ((const float2*)xc)[i];   // ds_read_b64, broadcast-ish

#pragma unroll
      for (int ky2 = 0; ky2 < 3; ++ky2) {
        const int row = oy + kyh * 3 + ky2;
        const float* zr = zc + row * KZZ;
        __align__(16) float zv[KZZ + 1];
#pragma unroll
        for (int i = 0; i < 11; ++i)
          ((float2*)zv)[i] = ((const float2*)zr)[i]; // 11 ds_read_b64, row in regs
#pragma unroll
        for (int kx = 0; kx < KXX; ++kx) {
          const float xs = xv[ky2 * KXX + kx];
#pragma unroll
          for (int ox = 0; ox < HO; ++ox)
            acc[ox] = fmaf(zv[ox + kx], xs, acc[ox]); // 17-wide register reuse
        }
      }
    }
  }

  // Cross-group reduction: 16 partials per output. Reuse zbuf as scratch.
  __syncthreads();
  float* red = &zbuf[0][0];   // needs 16*289 = 4624 floats <= 7744 available
  if (active) {
#pragma unroll
    for (int ox = 0; ox < HO; ++ox)
      red[g * OUTHW + oy * HO + ox] = acc[ox];
  }
  __syncthreads();
  if (t < OUTHW) {
    float s = 0.0f;
#pragma unroll
    for (int gg = 0; gg < 16; ++gg) s += red[gg * OUTHW + t];
    out[(size_t)b * OUTHW + t] = s;   // coalesced: consecutive t -> consecutive addr
  }
}

extern "C" void kernel_launch(void* const* d_in, const int* in_sizes, int n_in,
                              void* d_out, int out_size, void* d_ws, size_t ws_size,
                              hipStream_t stream) {
  const float* x = (const float*)d_in[0];   // [512,256,6,6]
  const float* z = (const float*)d_in[1];   // [512,256,22,22]
  float* out = (float*)d_out;               // [512,1,17,17]
  corr_kernel<<<BB, NT, 0, stream>>>(x, z, out);
}